// Round 1
// baseline (260.344 us; speedup 1.0000x reference)
//
#include <hip/hip_runtime.h>
#include <stdint.h>

typedef __bf16 bf16;
typedef __bf16 bf16x8 __attribute__((ext_vector_type(8)));
typedef __bf16 bf16x4 __attribute__((ext_vector_type(4)));
typedef float f32x4 __attribute__((ext_vector_type(4)));

__device__ inline void gload_lds16(const void* g, void* l) {
  __builtin_amdgcn_global_load_lds(
      (__attribute__((address_space(1))) void*)g,
      (__attribute__((address_space(3))) void*)l, 16, 0, 0);
}

__device__ inline void store_cast(float* p, float v) { *p = v; }
__device__ inline void store_cast(bf16* p, float v) { *p = (bf16)v; }

// ---------------- fp32 -> bf16 conversion (vectorized) ----------------
__global__ __launch_bounds__(256) void cvt_f32_bf16(const float* __restrict__ in,
                                                    bf16* __restrict__ out, int n4) {
  int i = blockIdx.x * blockDim.x + threadIdx.x;
  int stride = gridDim.x * blockDim.x;
  for (; i < n4; i += stride) {
    float4 v = ((const float4*)in)[i];
    bf16x4 o;
    o[0] = (bf16)v.x; o[1] = (bf16)v.y; o[2] = (bf16)v.z; o[3] = (bf16)v.w;
    ((bf16x4*)out)[i] = o;
  }
}

// ---------------- NT GEMM: C[M,N] = A[M,K] * B[N,K]^T  (m97 structure) ----------------
// 128x128 tile, BK=32, 4 waves (2x2), 16x16x32 bf16 MFMA, global_load_lds width 16.
template <typename OutT>
__global__ __launch_bounds__(256) void gemm_nt(
    const bf16* __restrict__ A, const bf16* __restrict__ Bm, OutT* __restrict__ C,
    int M, int N, int Kd, long sA, long sB, long sC, float scale)
{
  __shared__ bf16 As[128 * 32];
  __shared__ bf16 Bs[128 * 32];
  const int t = threadIdx.x;
  const int l = t & 63;
  const int fr = l & 15;        // fragment row/col within 16
  const int kch = l >> 4;       // k-chunk 0..3 (8 bf16 each)
  const int w = t >> 6;
  const int wr = w >> 1, wc = w & 1;
  const int m0 = blockIdx.y * 128;
  const int n0 = blockIdx.x * 128;
  const bf16* Ab = A + (long)blockIdx.z * sA;
  const bf16* Bb = Bm + (long)blockIdx.z * sB;
  OutT* Cb = C + (long)blockIdx.z * sC;

  f32x4 acc[4][4] = {};
  const int wbase = (t & 192) * 16;  // wave-uniform LDS byte base = w*1024

  for (int k0 = 0; k0 < Kd; k0 += 32) {
#pragma unroll
    for (int i = 0; i < 2; ++i) {
      const int c = i * 256 + t;          // chunk id 0..511; row=c>>2, 16B piece=c&3
      gload_lds16(Ab + (long)(m0 + (c >> 2)) * Kd + k0 + (c & 3) * 8,
                  (char*)As + i * 4096 + wbase);
      gload_lds16(Bb + (long)(n0 + (c >> 2)) * Kd + k0 + (c & 3) * 8,
                  (char*)Bs + i * 4096 + wbase);
    }
    __syncthreads();
    bf16x8 afrag[4], bfrag[4];
#pragma unroll
    for (int m = 0; m < 4; ++m)
      afrag[m] = *(const bf16x8*)((const char*)As + (wr * 64 + m * 16 + fr) * 64 + kch * 16);
#pragma unroll
    for (int n = 0; n < 4; ++n)
      bfrag[n] = *(const bf16x8*)((const char*)Bs + (wc * 64 + n * 16 + fr) * 64 + kch * 16);
#pragma unroll
    for (int m = 0; m < 4; ++m)
#pragma unroll
      for (int n = 0; n < 4; ++n)
        acc[m][n] = __builtin_amdgcn_mfma_f32_16x16x32_bf16(afrag[m], bfrag[n], acc[m][n], 0, 0, 0);
    __syncthreads();
  }

  // epilogue: C/D layout col=lane&15, row=(lane>>4)*4+reg
#pragma unroll
  for (int m = 0; m < 4; ++m)
#pragma unroll
    for (int n = 0; n < 4; ++n)
#pragma unroll
      for (int r = 0; r < 4; ++r) {
        const int row = m0 + wr * 64 + m * 16 + kch * 4 + r;
        const int col = n0 + wc * 64 + n * 16 + fr;
        store_cast(&Cb[(long)row * N + col], acc[m][n][r] * scale);
      }
}

// ---------------- bf16 transpose: per batch [S,D] -> [D,S] ----------------
__global__ __launch_bounds__(256) void transpose_bf16_k(const bf16* __restrict__ Vin,
                                                        bf16* __restrict__ Vout,
                                                        int S, int D) {
  __shared__ alignas(16) bf16 tile[64][72];
  const int t = threadIdx.x;
  const int s0 = blockIdx.y * 64;
  const int d0 = blockIdx.x * 64;
  const bf16* Vb = Vin + (long)blockIdx.z * S * D;
  bf16* Ob = Vout + (long)blockIdx.z * D * S;
  const int r = t >> 3;          // 0..31
  const int c8 = (t & 7) * 8;    // 0..56
#pragma unroll
  for (int i = 0; i < 2; ++i) {
    bf16x8 v = *(const bf16x8*)(Vb + (long)(s0 + r + i * 32) * D + d0 + c8);
    *(bf16x8*)&tile[r + i * 32][c8] = v;
  }
  __syncthreads();
#pragma unroll
  for (int i = 0; i < 2; ++i) {
    const int dd = r + i * 32;
    bf16x8 o;
#pragma unroll
    for (int j = 0; j < 8; ++j) o[j] = tile[c8 + j][dd];
    *(bf16x8*)(Ob + (long)(d0 + dd) * S + s0 + c8) = o;
  }
}

// ---------------- row softmax: fp32 scores -> bf16 P ----------------
__global__ __launch_bounds__(256) void softmax_k(const float* __restrict__ Sm,
                                                 bf16* __restrict__ P, int cols) {
  __shared__ float red[8];
  const long row = blockIdx.x;
  const float* sr = Sm + row * (long)cols;
  bf16* pr = P + row * (long)cols;
  const int t = threadIdx.x;
  float4 a = ((const float4*)sr)[2 * t];
  float4 b = ((const float4*)sr)[2 * t + 1];
  float e[8] = {a.x, a.y, a.z, a.w, b.x, b.y, b.z, b.w};
  float m = e[0];
#pragma unroll
  for (int j = 1; j < 8; ++j) m = fmaxf(m, e[j]);
#pragma unroll
  for (int o = 32; o; o >>= 1) m = fmaxf(m, __shfl_xor(m, o));
  if ((t & 63) == 0) red[t >> 6] = m;
  __syncthreads();
  m = fmaxf(fmaxf(red[0], red[1]), fmaxf(red[2], red[3]));
  float s = 0.f;
#pragma unroll
  for (int j = 0; j < 8; ++j) { e[j] = __expf(e[j] - m); s += e[j]; }
#pragma unroll
  for (int o = 32; o; o >>= 1) s += __shfl_xor(s, o);
  if ((t & 63) == 0) red[4 + (t >> 6)] = s;
  __syncthreads();
  s = red[4] + red[5] + red[6] + red[7];
  const float inv = 1.0f / s;
  bf16x8 o8;
#pragma unroll
  for (int j = 0; j < 8; ++j) o8[j] = (bf16)(e[j] * inv);
  *(bf16x8*)(pr + t * 8) = o8;
}

extern "C" void kernel_launch(void* const* d_in, const int* in_sizes, int n_in,
                              void* d_out, int out_size, void* d_ws, size_t ws_size,
                              hipStream_t stream) {
  const float* x  = (const float*)d_in[0];
  const float* Wq = (const float*)d_in[1];
  const float* Wk = (const float*)d_in[2];
  const float* Wv = (const float*)d_in[3];
  float* out = (float*)d_out;

  const int B = 4, S = 2048, D = 1024;
  const long MS = (long)B * S;  // 8192

  // workspace layout (bytes):
  //  [0, 16.78M)   Q            -> later reused (with K region) as P (bf16, 33.55M)
  //  [16.78M, 33.55M)  K
  //  [33.55M, 50.33M)  Vt
  //  [50.33M, 117.44M) scores (fp32, 67.11M); before QK^T this region holds xb, Wb, V
  char* ws = (char*)d_ws;
  const long SZ = 16777216;  // 16 MiB region unit (8192*1024*2)
  bf16* Q   = (bf16*)(ws);
  bf16* Kn  = (bf16*)(ws + SZ);
  bf16* Vt  = (bf16*)(ws + 2 * SZ);
  float* sc = (float*)(ws + 3 * SZ);
  bf16* P   = (bf16*)(ws);
  bf16* xb  = (bf16*)(ws + 3 * SZ);
  bf16* Wb  = (bf16*)(ws + 4 * SZ);
  bf16* V   = (bf16*)(ws + 4 * SZ + 3 * 2097152);

  dim3 blk(256, 1, 1);

  // 1) convert inputs to bf16
  cvt_f32_bf16<<<2048, blk, 0, stream>>>(x, xb, (int)(MS * D / 4));
  cvt_f32_bf16<<<512, blk, 0, stream>>>(Wq, Wb,             D * D / 4);
  cvt_f32_bf16<<<512, blk, 0, stream>>>(Wk, Wb + 1048576,   D * D / 4);
  cvt_f32_bf16<<<512, blk, 0, stream>>>(Wv, Wb + 2097152,   D * D / 4);

  // 2) projections: [8192,1024] = xb [8192,1024] @ W[1024,1024]^T
  dim3 gproj(1024 / 128, 8192 / 128, 1);
  gemm_nt<bf16><<<gproj, blk, 0, stream>>>(xb, Wb,           Q,  8192, 1024, 1024, 0, 0, 0, 1.f);
  gemm_nt<bf16><<<gproj, blk, 0, stream>>>(xb, Wb + 1048576, Kn, 8192, 1024, 1024, 0, 0, 0, 1.f);
  gemm_nt<bf16><<<gproj, blk, 0, stream>>>(xb, Wb + 2097152, V,  8192, 1024, 1024, 0, 0, 0, 1.f);

  // 3) transpose V -> Vt (per batch [S,D] -> [D,S])
  dim3 gtr(1024 / 64, 2048 / 64, 4);
  transpose_bf16_k<<<gtr, blk, 0, stream>>>(V, Vt, S, D);

  // 4) scores = Q @ K^T / 32  (batched, fp32 out)
  dim3 gqk(2048 / 128, 2048 / 128, 4);
  gemm_nt<float><<<gqk, blk, 0, stream>>>(Q, Kn, sc, 2048, 2048, 1024,
                                          (long)S * D, (long)S * D, (long)S * S, 0.03125f);

  // 5) softmax rows -> bf16 P (overwrites dead Q/K region)
  softmax_k<<<8192, blk, 0, stream>>>(sc, P, 2048);

  // 6) out = P @ Vt^T (batched; Vt is [D,S] so NT gives P[2048,2048] @ V[2048,1024])
  dim3 gpv(1024 / 128, 2048 / 128, 4);
  gemm_nt<float><<<gpv, blk, 0, stream>>>(P, Vt, out, 2048, 1024, 2048,
                                          (long)S * S, (long)D * S, (long)S * D, 1.f);
}

// Round 2
// 214.001 us; speedup vs baseline: 1.2166x; 1.2166x over previous
//
#include <hip/hip_runtime.h>
#include <stdint.h>

typedef __bf16 bf16;
typedef __bf16 bf16x8 __attribute__((ext_vector_type(8)));
typedef __bf16 bf16x4 __attribute__((ext_vector_type(4)));
typedef float f32x4 __attribute__((ext_vector_type(4)));

__device__ inline void gload_lds16(const void* g, void* l) {
  __builtin_amdgcn_global_load_lds(
      (__attribute__((address_space(1))) void*)g,
      (__attribute__((address_space(3))) void*)l, 16, 0, 0);
}

// ---------------- fp32 -> bf16 conversion (vectorized) ----------------
__global__ __launch_bounds__(256) void cvt_f32_bf16(const float* __restrict__ in,
                                                    bf16* __restrict__ out, int n4) {
  int i = blockIdx.x * blockDim.x + threadIdx.x;
  int stride = gridDim.x * blockDim.x;
  for (; i < n4; i += stride) {
    float4 v = ((const float4*)in)[i];
    bf16x4 o;
    o[0] = (bf16)v.x; o[1] = (bf16)v.y; o[2] = (bf16)v.z; o[3] = (bf16)v.w;
    ((bf16x4*)out)[i] = o;
  }
}

// =====================================================================
// 256x256 8-phase GEMM (T2-free conflict-free LDS + T3/T4 counted vmcnt + T5)
// C[M,N] = A[M,K] * B[N,K]^T.  BK=64, 512 threads (8 waves, 2Mx4N).
// LDS 128 KiB: buf{0,1} x { A: [k0 16K][k1 16K] , B: [k0 16K][k1 16K] }.
// Region layout: 16B unit at (r, chunk): holds row (e>>2)*128 + r,
// k-chunk (e&3), where e = chunk ^ (r&7).  Linear global_load_lds dest +
// pre-swizzled global source; ds_read_b128 hits each bank-quad exactly
// 8 lanes -> conflict-free.
// MODE 0: proj (bf16 out; col<2048 -> Cg ldc=2048, col>=2048 -> C2g ld=1024)
// MODE 1: fp32 out with scale (ldc param)
// =====================================================================
template <int MODE>
__global__ __launch_bounds__(512, 2) void gemm8(
    const bf16* __restrict__ Ag, const bf16* __restrict__ Bg,
    void* __restrict__ Cg, void* __restrict__ C2g,
    long lda, long ldb, long ldc,
    long sA, long sB, long sC, int K, float scale)
{
  __shared__ alignas(16) char lds[131072];
  const int tid = threadIdx.x;
  const int l = tid & 63;
  const int wv = tid >> 6;
  const int wm = wv >> 2;   // 0..1
  const int wn = wv & 3;    // 0..3
  const int fr = l & 15;
  const int kch = l >> 4;
  const int m0 = blockIdx.y * 256;
  const int n0 = blockIdx.x * 256;
  const bf16* Ab = Ag + (long)blockIdx.z * sA;
  const bf16* Bb = Bg + (long)blockIdx.z * sB;

  // fragment-read byte offsets within a 16KB k-region
  const int a_rd = fr * 128 + (((wm * 4 + kch) ^ (fr & 7)) << 4);
  const int b_rd = (wn & 1) * 8192 + fr * 128 + ((((wn >> 1) * 4 + kch) ^ (fr & 7)) << 4);

  // staging constants (inverse swizzle): thread tid, round rd handles
  // linear 16B unit p = rd*512+tid -> r=p>>3, chunk=p&7, e=chunk^(r&7)
  const int se = (tid & 7) ^ ((tid >> 3) & 7);
  const int s_row = (se >> 2) * 128 + (tid >> 3);  // + rd*64
  const int s_k = (se & 3) * 8;
  const int wbase = (tid & 448) * 16;  // wave-uniform lds offset

  const int NT = K >> 6;
  f32x4 acc[8][4] = {};

  auto stageA = [&](int tile, int kh, int buf) {
#pragma unroll
    for (int rd = 0; rd < 2; ++rd)
      gload_lds16(Ab + (long)(m0 + s_row + rd * 64) * lda + tile * 64 + kh * 32 + s_k,
                  lds + buf * 65536 + kh * 16384 + rd * 8192 + wbase);
  };
  auto stageB = [&](int tile, int kh, int buf) {
#pragma unroll
    for (int rd = 0; rd < 2; ++rd)
      gload_lds16(Bb + (long)(n0 + s_row + rd * 64) * ldb + tile * 64 + kh * 32 + s_k,
                  lds + buf * 65536 + 32768 + kh * 16384 + rd * 8192 + wbase);
  };

#define PHASE(KH, MH, STAGE_STMT)                                              \
  {                                                                            \
    bf16x8 af[4], bfg[4];                                                      \
    _Pragma("unroll")                                                          \
    for (int m = 0; m < 4; ++m)                                                \
      af[m] = *(const bf16x8*)(bufA + (KH) * 16384 + (MH) * 8192 + m * 2048 + a_rd); \
    _Pragma("unroll")                                                          \
    for (int n = 0; n < 4; ++n)                                                \
      bfg[n] = *(const bf16x8*)(bufB + (KH) * 16384 + n * 2048 + b_rd);        \
    STAGE_STMT;                                                                \
    __builtin_amdgcn_s_barrier();                                              \
    __builtin_amdgcn_s_setprio(1);                                             \
    _Pragma("unroll")                                                          \
    for (int m = 0; m < 4; ++m)                                                \
      _Pragma("unroll")                                                        \
      for (int n = 0; n < 4; ++n)                                              \
        acc[(MH) * 4 + m][n] = __builtin_amdgcn_mfma_f32_16x16x32_bf16(        \
            af[m], bfg[n], acc[(MH) * 4 + m][n], 0, 0, 0);                     \
    __builtin_amdgcn_s_setprio(0);                                             \
  }

  // prologue: tile0 all 4 regions -> buf0; tile1 r0,r1 (k0 halves) -> buf1
  stageA(0, 0, 0); stageB(0, 0, 0); stageA(0, 1, 0); stageB(0, 1, 0);
  {
    const int t1p = min(1, NT - 1);
    stageA(t1p, 0, 1); stageB(t1p, 0, 1);
  }
  asm volatile("s_waitcnt vmcnt(4)" ::: "memory");
  __builtin_amdgcn_sched_barrier(0);
  __builtin_amdgcn_s_barrier();

  for (int t = 0; t < NT; ++t) {
    const char* bufA = lds + (t & 1) * 65536;
    const char* bufB = bufA + 32768;
    const int t1 = min(t + 1, NT - 1);
    const int t2 = min(t + 2, NT - 1);
    const int nb = (t & 1) ^ 1;
    PHASE(0, 0, stageA(t1, 1, nb));        // stage (t+1) A-k1
    __builtin_amdgcn_s_barrier();
    PHASE(0, 1, stageB(t1, 1, nb));        // stage (t+1) B-k1
    __builtin_amdgcn_s_barrier();
    PHASE(1, 0, stageA(t2, 0, t & 1));     // stage (t+2) A-k0
    __builtin_amdgcn_s_barrier();
    PHASE(1, 1, stageB(t2, 0, t & 1));     // stage (t+2) B-k0
    asm volatile("s_waitcnt vmcnt(4)" ::: "memory");
    __builtin_amdgcn_sched_barrier(0);
    __builtin_amdgcn_s_barrier();
  }
#undef PHASE
  asm volatile("s_waitcnt vmcnt(0)" ::: "memory");

  // epilogue: C/D layout col=lane&15, row=(lane>>4)*4+reg
#pragma unroll
  for (int mf = 0; mf < 8; ++mf) {
    const int row = m0 + wm * 128 + (mf >> 2) * 64 + (mf & 3) * 16 + (l >> 4) * 4;
#pragma unroll
    for (int n = 0; n < 4; ++n) {
      const int col = n0 + wn * 64 + n * 16 + fr;
      if (MODE == 0) {
        if (col < 2048) {
          bf16* C = (bf16*)Cg;
#pragma unroll
          for (int r = 0; r < 4; ++r)
            C[(long)(row + r) * ldc + col] = (bf16)acc[mf][n][r];
        } else {
          bf16* C2 = (bf16*)C2g;
#pragma unroll
          for (int r = 0; r < 4; ++r)
            C2[(long)(row + r) * 1024 + (col - 2048)] = (bf16)acc[mf][n][r];
        }
      } else {
        float* C = (float*)Cg + (long)blockIdx.z * sC;
#pragma unroll
        for (int r = 0; r < 4; ++r)
          C[(long)(row + r) * ldc + col] = acc[mf][n][r] * scale;
      }
    }
  }
}

// ---------------- NT GEMM 128^2 (m97 structure) — kept for PV ----------------
template <typename OutT>
__global__ __launch_bounds__(256) void gemm_nt(
    const bf16* __restrict__ A, const bf16* __restrict__ Bm, OutT* __restrict__ C,
    int M, int N, int Kd, long sA, long sB, long sC, float scale)
{
  __shared__ bf16 As[128 * 32];
  __shared__ bf16 Bs[128 * 32];
  const int t = threadIdx.x;
  const int l = t & 63;
  const int fr = l & 15;
  const int kch = l >> 4;
  const int w = t >> 6;
  const int wr = w >> 1, wc = w & 1;
  const int m0 = blockIdx.y * 128;
  const int n0 = blockIdx.x * 128;
  const bf16* Ab = A + (long)blockIdx.z * sA;
  const bf16* Bb = Bm + (long)blockIdx.z * sB;
  OutT* Cb = C + (long)blockIdx.z * sC;

  f32x4 acc[4][4] = {};
  const int wbase = (t & 192) * 16;

  for (int k0 = 0; k0 < Kd; k0 += 32) {
#pragma unroll
    for (int i = 0; i < 2; ++i) {
      const int c = i * 256 + t;
      gload_lds16(Ab + (long)(m0 + (c >> 2)) * Kd + k0 + (c & 3) * 8,
                  (char*)As + i * 4096 + wbase);
      gload_lds16(Bb + (long)(n0 + (c >> 2)) * Kd + k0 + (c & 3) * 8,
                  (char*)Bs + i * 4096 + wbase);
    }
    __syncthreads();
    bf16x8 afrag[4], bfrag[4];
#pragma unroll
    for (int m = 0; m < 4; ++m)
      afrag[m] = *(const bf16x8*)((const char*)As + (wr * 64 + m * 16 + fr) * 64 + kch * 16);
#pragma unroll
    for (int n = 0; n < 4; ++n)
      bfrag[n] = *(const bf16x8*)((const char*)Bs + (wc * 64 + n * 16 + fr) * 64 + kch * 16);
#pragma unroll
    for (int m = 0; m < 4; ++m)
#pragma unroll
      for (int n = 0; n < 4; ++n)
        acc[m][n] = __builtin_amdgcn_mfma_f32_16x16x32_bf16(afrag[m], bfrag[n], acc[m][n], 0, 0, 0);
    __syncthreads();
  }
#pragma unroll
  for (int m = 0; m < 4; ++m)
#pragma unroll
    for (int n = 0; n < 4; ++n)
#pragma unroll
      for (int r = 0; r < 4; ++r) {
        const int row = m0 + wr * 64 + m * 16 + kch * 4 + r;
        const int col = n0 + wc * 64 + n * 16 + fr;
        Cb[(long)row * N + col] = (OutT)(acc[m][n][r] * scale);
      }
}

// ---------------- bf16 transpose: per batch [S,D] -> [D,S] ----------------
__global__ __launch_bounds__(256) void transpose_bf16_k(const bf16* __restrict__ Vin,
                                                        bf16* __restrict__ Vout,
                                                        int S, int D) {
  __shared__ alignas(16) bf16 tile[64][72];
  const int t = threadIdx.x;
  const int s0 = blockIdx.y * 64;
  const int d0 = blockIdx.x * 64;
  const bf16* Vb = Vin + (long)blockIdx.z * S * D;
  bf16* Ob = Vout + (long)blockIdx.z * D * S;
  const int r = t >> 3;
  const int c8 = (t & 7) * 8;
#pragma unroll
  for (int i = 0; i < 2; ++i) {
    bf16x8 v = *(const bf16x8*)(Vb + (long)(s0 + r + i * 32) * D + d0 + c8);
    *(bf16x8*)&tile[r + i * 32][c8] = v;
  }
  __syncthreads();
#pragma unroll
  for (int i = 0; i < 2; ++i) {
    const int dd = r + i * 32;
    bf16x8 o;
#pragma unroll
    for (int j = 0; j < 8; ++j) o[j] = tile[c8 + j][dd];
    *(bf16x8*)(Ob + (long)(d0 + dd) * S + s0 + c8) = o;
  }
}

// ---------------- row softmax: fp32 scores -> bf16 P ----------------
__global__ __launch_bounds__(256) void softmax_k(const float* __restrict__ Sm,
                                                 bf16* __restrict__ P, int cols) {
  __shared__ float red[8];
  const long row = blockIdx.x;
  const float* sr = Sm + row * (long)cols;
  bf16* pr = P + row * (long)cols;
  const int t = threadIdx.x;
  float4 a = ((const float4*)sr)[2 * t];
  float4 b = ((const float4*)sr)[2 * t + 1];
  float e[8] = {a.x, a.y, a.z, a.w, b.x, b.y, b.z, b.w};
  float m = e[0];
#pragma unroll
  for (int j = 1; j < 8; ++j) m = fmaxf(m, e[j]);
#pragma unroll
  for (int o = 32; o; o >>= 1) m = fmaxf(m, __shfl_xor(m, o));
  if ((t & 63) == 0) red[t >> 6] = m;
  __syncthreads();
  m = fmaxf(fmaxf(red[0], red[1]), fmaxf(red[2], red[3]));
  float s = 0.f;
#pragma unroll
  for (int j = 0; j < 8; ++j) { e[j] = __expf(e[j] - m); s += e[j]; }
#pragma unroll
  for (int o = 32; o; o >>= 1) s += __shfl_xor(s, o);
  if ((t & 63) == 0) red[4 + (t >> 6)] = s;
  __syncthreads();
  s = red[4] + red[5] + red[6] + red[7];
  const float inv = 1.0f / s;
  bf16x8 o8;
#pragma unroll
  for (int j = 0; j < 8; ++j) o8[j] = (bf16)(e[j] * inv);
  *(bf16x8*)(pr + t * 8) = o8;
}

extern "C" void kernel_launch(void* const* d_in, const int* in_sizes, int n_in,
                              void* d_out, int out_size, void* d_ws, size_t ws_size,
                              hipStream_t stream) {
  const float* x  = (const float*)d_in[0];
  const float* Wq = (const float*)d_in[1];
  const float* Wk = (const float*)d_in[2];
  const float* Wv = (const float*)d_in[3];
  float* out = (float*)d_out;

  const int S = 2048, D = 1024;

  // workspace (117.44 MB total, same footprint as round 1):
  //  [0, 33.55M)        QKbuf bf16 [8192][2048]  -> later P bf16 (softmax out)
  //  [33.55M, 50.33M)   Vt bf16 [4][1024][2048]
  //  [50.33M, 117.44M)  scores fp32 [4][2048][2048]
  //     (pre-QK this region holds: xb @50.33M (16.78M), Wb @67.11M (6.29M),
  //      Vtmp @73.40M (16.78M) — all dead before QK writes scores)
  char* ws = (char*)d_ws;
  bf16* QKbuf = (bf16*)(ws);
  bf16* P     = (bf16*)(ws);
  bf16* Vt    = (bf16*)(ws + 33554432);
  float* sc   = (float*)(ws + 50331648);
  bf16* xb    = (bf16*)(ws + 50331648);
  bf16* Wb    = (bf16*)(ws + 67108864);
  bf16* Vtmp  = (bf16*)(ws + 73400320);

  dim3 b256(256, 1, 1), b512(512, 1, 1);

  // 1) convert inputs to bf16 (W's packed contiguous: [3][1024][1024])
  cvt_f32_bf16<<<2048, b256, 0, stream>>>(x, xb, 8192 * 1024 / 4);
  cvt_f32_bf16<<<512, b256, 0, stream>>>(Wq, Wb,             D * D / 4);
  cvt_f32_bf16<<<512, b256, 0, stream>>>(Wk, Wb + 1048576,   D * D / 4);
  cvt_f32_bf16<<<512, b256, 0, stream>>>(Wv, Wb + 2097152,   D * D / 4);

  // 2) fused QKV projection: [8192,3072] = xb @ Wb^T; Q/K packed -> QKbuf, V -> Vtmp
  gemm8<0><<<dim3(12, 32, 1), b512, 0, stream>>>(
      xb, Wb, QKbuf, Vtmp, 1024, 1024, 2048, 0, 0, 0, 1024, 1.f);

  // 3) transpose Vtmp [S,D] -> Vt [D,S] per batch
  transpose_bf16_k<<<dim3(16, 32, 4), b256, 0, stream>>>(Vtmp, Vt, S, D);

  // 4) scores = Q @ K^T / 32 (batched; Q at col 0, K at col 1024 of QKbuf)
  gemm8<1><<<dim3(8, 8, 4), b512, 0, stream>>>(
      QKbuf, QKbuf + 1024, sc, nullptr, 2048, 2048, 2048,
      4194304, 4194304, 4194304, 1024, 0.03125f);

  // 5) softmax rows -> bf16 P (overwrites dead QKbuf)
  softmax_k<<<8192, b256, 0, stream>>>(sc, P, 2048);

  // 6) out = P @ Vt^T (batched 128^2 kernel; 512 blocks)
  gemm_nt<float><<<dim3(8, 16, 4), b256, 0, stream>>>(
      P, Vt, out, 2048, 1024, 2048, 4194304, 2097152, 2097152, 1.f);
}

// Round 3
// 189.841 us; speedup vs baseline: 1.3714x; 1.1273x over previous
//
#include <hip/hip_runtime.h>
#include <stdint.h>

typedef __bf16 bf16;
typedef __bf16 bf16x8 __attribute__((ext_vector_type(8)));
typedef __bf16 bf16x4 __attribute__((ext_vector_type(4)));
typedef float f32x4 __attribute__((ext_vector_type(4)));

__device__ inline void gload_lds16(const void* g, void* l) {
  __builtin_amdgcn_global_load_lds(
      (__attribute__((address_space(1))) void*)g,
      (__attribute__((address_space(3))) void*)l, 16, 0, 0);
}

// ---------------- fp32 -> bf16 conversion (vectorized) ----------------
__global__ __launch_bounds__(256) void cvt_f32_bf16(const float* __restrict__ in,
                                                    bf16* __restrict__ out, int n4) {
  int i = blockIdx.x * blockDim.x + threadIdx.x;
  int stride = gridDim.x * blockDim.x;
  for (; i < n4; i += stride) {
    float4 v = ((const float4*)in)[i];
    bf16x4 o;
    o[0] = (bf16)v.x; o[1] = (bf16)v.y; o[2] = (bf16)v.z; o[3] = (bf16)v.w;
    ((bf16x4*)out)[i] = o;
  }
}

// =====================================================================
// 8-phase GEMM, BM=256, BK=64, 512 threads.  C[M,N] = A[M,K]*B[N,K]^T.
// BN=256: waves 2Mx4N (wave tile 128x64), LDS 128K, B-frags cached across
//         MH phases (24 ds_read_b128/wave/K-tile instead of 32).
// BN=128: waves 4Mx2N (wave tile 64x64), LDS 96K, 2 phases per K-tile.
// Swizzled conflict-free LDS regions (verified 0 bank conflicts in r2):
//   16B unit (r, chunk) of a region holds row' = (e>>2)*(R/2) + r,
//   k-chunk e&3, where e = chunk ^ (r&7).  Linear gload_lds dest +
//   inverse-swizzled global source.
// MODE 0: proj epilogue (col<2048 -> bf16 C ld 2048; col>=2048 -> V^T
//         into C2g as [4][1024][2048])
// MODE 1: fp32 out with scale
// =====================================================================
template <int MODE, int BN>
__global__ __launch_bounds__(512, 2) void gemm8(
    const bf16* __restrict__ Ag, const bf16* __restrict__ Bg,
    void* __restrict__ Cg, void* __restrict__ C2g,
    long lda, long ldb, long ldc,
    long sA, long sB, long sC, int K, float scale)
{
  constexpr int BUFSZ = 32768 + BN * 128;
  constexpr int MACC = (BN == 256) ? 8 : 4;
  __shared__ alignas(16) char lds[2 * BUFSZ];
  const int tid = threadIdx.x;
  const int l = tid & 63;
  const int wv = tid >> 6;
  const int fr = l & 15;
  const int kch = l >> 4;
  const int m0 = blockIdx.y * 256;
  const int n0 = blockIdx.x * BN;
  const bf16* Ab = Ag + (long)blockIdx.z * sA;
  const bf16* Bb = Bg + (long)blockIdx.z * sB;

  const int wm = (BN == 256) ? (wv >> 2) : (wv >> 1);
  const int wn = (BN == 256) ? (wv & 3) : (wv & 1);

  // fragment-read byte offsets
  int a_rd, b_rd;
  if constexpr (BN == 256) {
    a_rd = fr * 128 + (((wm * 4 + kch) ^ (fr & 7)) << 4);                 // +KH*16384+MH*8192+m*2048
    b_rd = (wn & 1) * 8192 + fr * 128 + ((((wn >> 1) * 4 + kch) ^ (fr & 7)) << 4); // +KH*16384+n*2048
  } else {
    a_rd = (wm & 1) * 8192 + fr * 128 + ((((wm >> 1) * 4 + kch) ^ (fr & 7)) << 4); // +KH*16384+m*2048
    b_rd = fr * 128 + (((wn * 4 + kch) ^ (fr & 7)) << 4);                 // +KH*8192+n*2048
  }

  // staging (inverse swizzle), linear LDS dest
  const int se = (tid & 7) ^ ((tid >> 3) & 7);
  const int s_rowA = (se >> 2) * 128 + (tid >> 3);
  const int s_rowB = (BN == 256) ? s_rowA : ((se >> 2) * 64 + (tid >> 3));
  const int s_k = (se & 3) * 8;
  const int wb16 = (tid & 448) * 16;

  const int NT = K >> 6;
  f32x4 acc[MACC][4] = {};

  auto stageA = [&](int tile, int kh, int buf) {
#pragma unroll
    for (int rd = 0; rd < 2; ++rd)
      gload_lds16(Ab + (long)(m0 + s_rowA + rd * 64) * lda + tile * 64 + kh * 32 + s_k,
                  lds + buf * BUFSZ + kh * 16384 + rd * 8192 + wb16);
  };
  auto stageB = [&](int tile, int kh, int buf) {
    if constexpr (BN == 256) {
#pragma unroll
      for (int rd = 0; rd < 2; ++rd)
        gload_lds16(Bb + (long)(n0 + s_rowB + rd * 64) * ldb + tile * 64 + kh * 32 + s_k,
                    lds + buf * BUFSZ + 32768 + kh * 16384 + rd * 8192 + wb16);
    } else {
      gload_lds16(Bb + (long)(n0 + s_rowB) * ldb + tile * 64 + kh * 32 + s_k,
                  lds + buf * BUFSZ + 32768 + kh * 8192 + wb16);
    }
  };

  // prologue: tile0 fully -> buf0, tile1 k0 -> buf1
  stageA(0, 0, 0); stageB(0, 0, 0); stageA(0, 1, 0); stageB(0, 1, 0);
  stageA(min(1, NT - 1), 0, 1); stageB(min(1, NT - 1), 0, 1);
  if constexpr (BN == 256) asm volatile("s_waitcnt vmcnt(4)" ::: "memory");
  else                     asm volatile("s_waitcnt vmcnt(3)" ::: "memory");
  __builtin_amdgcn_sched_barrier(0);
  __builtin_amdgcn_s_barrier();

  for (int t = 0; t < NT; ++t) {
    const char* bufA = lds + (t & 1) * BUFSZ;
    const char* bufB = bufA + 32768;
    const int t1 = min(t + 1, NT - 1);
    const int t2 = min(t + 2, NT - 1);
    const int nb = (t & 1) ^ 1;
    const int cur = t & 1;

    if constexpr (BN == 256) {
      bf16x8 bfg[4], af[4];
      // P1: B(KH0) + A(KH0,MH0)
#pragma unroll
      for (int n = 0; n < 4; ++n) bfg[n] = *(const bf16x8*)(bufB + n * 2048 + b_rd);
#pragma unroll
      for (int m = 0; m < 4; ++m) af[m] = *(const bf16x8*)(bufA + m * 2048 + a_rd);
      stageA(t1, 1, nb);
      __builtin_amdgcn_s_barrier();
      __builtin_amdgcn_s_setprio(1);
#pragma unroll
      for (int m = 0; m < 4; ++m)
#pragma unroll
        for (int n = 0; n < 4; ++n)
          acc[m][n] = __builtin_amdgcn_mfma_f32_16x16x32_bf16(af[m], bfg[n], acc[m][n], 0, 0, 0);
      __builtin_amdgcn_s_setprio(0);
      __builtin_amdgcn_s_barrier();
      // P2: A(KH0,MH1), B cached
#pragma unroll
      for (int m = 0; m < 4; ++m) af[m] = *(const bf16x8*)(bufA + 8192 + m * 2048 + a_rd);
      stageB(t1, 1, nb);
      __builtin_amdgcn_s_barrier();
      __builtin_amdgcn_s_setprio(1);
#pragma unroll
      for (int m = 0; m < 4; ++m)
#pragma unroll
        for (int n = 0; n < 4; ++n)
          acc[4 + m][n] = __builtin_amdgcn_mfma_f32_16x16x32_bf16(af[m], bfg[n], acc[4 + m][n], 0, 0, 0);
      __builtin_amdgcn_s_setprio(0);
      __builtin_amdgcn_s_barrier();
      // P3: B(KH1) + A(KH1,MH0)
#pragma unroll
      for (int n = 0; n < 4; ++n) bfg[n] = *(const bf16x8*)(bufB + 16384 + n * 2048 + b_rd);
#pragma unroll
      for (int m = 0; m < 4; ++m) af[m] = *(const bf16x8*)(bufA + 16384 + m * 2048 + a_rd);
      stageA(t2, 0, cur);
      __builtin_amdgcn_s_barrier();
      __builtin_amdgcn_s_setprio(1);
#pragma unroll
      for (int m = 0; m < 4; ++m)
#pragma unroll
        for (int n = 0; n < 4; ++n)
          acc[m][n] = __builtin_amdgcn_mfma_f32_16x16x32_bf16(af[m], bfg[n], acc[m][n], 0, 0, 0);
      __builtin_amdgcn_s_setprio(0);
      __builtin_amdgcn_s_barrier();
      // P4: A(KH1,MH1), B cached
#pragma unroll
      for (int m = 0; m < 4; ++m) af[m] = *(const bf16x8*)(bufA + 16384 + 8192 + m * 2048 + a_rd);
      stageB(t2, 0, cur);
      __builtin_amdgcn_s_barrier();
      __builtin_amdgcn_s_setprio(1);
#pragma unroll
      for (int m = 0; m < 4; ++m)
#pragma unroll
        for (int n = 0; n < 4; ++n)
          acc[4 + m][n] = __builtin_amdgcn_mfma_f32_16x16x32_bf16(af[m], bfg[n], acc[4 + m][n], 0, 0, 0);
      __builtin_amdgcn_s_setprio(0);
      asm volatile("s_waitcnt vmcnt(4)" ::: "memory");
      __builtin_amdgcn_sched_barrier(0);
      __builtin_amdgcn_s_barrier();
    } else {
      bf16x8 bfg[4], af[4];
      // P1: KH0
#pragma unroll
      for (int n = 0; n < 4; ++n) bfg[n] = *(const bf16x8*)(bufB + n * 2048 + b_rd);
#pragma unroll
      for (int m = 0; m < 4; ++m) af[m] = *(const bf16x8*)(bufA + m * 2048 + a_rd);
      stageA(t1, 1, nb); stageB(t1, 1, nb);
      __builtin_amdgcn_s_barrier();
      __builtin_amdgcn_s_setprio(1);
#pragma unroll
      for (int m = 0; m < 4; ++m)
#pragma unroll
        for (int n = 0; n < 4; ++n)
          acc[m][n] = __builtin_amdgcn_mfma_f32_16x16x32_bf16(af[m], bfg[n], acc[m][n], 0, 0, 0);
      __builtin_amdgcn_s_setprio(0);
      __builtin_amdgcn_s_barrier();
      // P2: KH1
#pragma unroll
      for (int n = 0; n < 4; ++n) bfg[n] = *(const bf16x8*)(bufB + 8192 + n * 2048 + b_rd);
#pragma unroll
      for (int m = 0; m < 4; ++m) af[m] = *(const bf16x8*)(bufA + 16384 + m * 2048 + a_rd);
      stageA(t2, 0, cur); stageB(t2, 0, cur);
      __builtin_amdgcn_s_barrier();
      __builtin_amdgcn_s_setprio(1);
#pragma unroll
      for (int m = 0; m < 4; ++m)
#pragma unroll
        for (int n = 0; n < 4; ++n)
          acc[m][n] = __builtin_amdgcn_mfma_f32_16x16x32_bf16(af[m], bfg[n], acc[m][n], 0, 0, 0);
      __builtin_amdgcn_s_setprio(0);
      asm volatile("s_waitcnt vmcnt(3)" ::: "memory");
      __builtin_amdgcn_sched_barrier(0);
      __builtin_amdgcn_s_barrier();
    }
  }
  asm volatile("s_waitcnt vmcnt(0)" ::: "memory");

  // epilogue: C/D layout col=lane&15, row=(lane>>4)*4+reg
#pragma unroll
  for (int mf = 0; mf < MACC; ++mf) {
    int row;
    if constexpr (BN == 256)
      row = m0 + wm * 128 + (mf >> 2) * 64 + (mf & 3) * 16 + (l >> 4) * 4;
    else
      row = m0 + wm * 64 + mf * 16 + (l >> 4) * 4;
#pragma unroll
    for (int n = 0; n < 4; ++n) {
      const int col = n0 + wn * 64 + n * 16 + fr;
      if constexpr (MODE == 0) {
        if (col < 2048) {
          bf16* C = (bf16*)Cg;
#pragma unroll
          for (int r = 0; r < 4; ++r)
            C[(long)(row + r) * 2048 + col] = (bf16)acc[mf][n][r];
        } else {
          bf16* Vt = (bf16*)C2g;
          const int d = col - 2048;
          const int b = row >> 11;
          const int s = row & 2047;
          bf16x4 pk;
#pragma unroll
          for (int r = 0; r < 4; ++r) pk[r] = (bf16)acc[mf][n][r];
          *(bf16x4*)(Vt + (long)b * 2097152 + (long)d * 2048 + s) = pk;
        }
      } else {
        float* C = (float*)Cg + (long)blockIdx.z * sC;
#pragma unroll
        for (int r = 0; r < 4; ++r)
          C[(long)(row + r) * ldc + col] = acc[mf][n][r] * scale;
      }
    }
  }
}

// ---------------- row softmax: fp32 scores -> bf16 P ----------------
__global__ __launch_bounds__(256) void softmax_k(const float* __restrict__ Sm,
                                                 bf16* __restrict__ P, int cols) {
  __shared__ float red[8];
  const long row = blockIdx.x;
  const float* sr = Sm + row * (long)cols;
  bf16* pr = P + row * (long)cols;
  const int t = threadIdx.x;
  float4 a = ((const float4*)sr)[2 * t];
  float4 b = ((const float4*)sr)[2 * t + 1];
  float e[8] = {a.x, a.y, a.z, a.w, b.x, b.y, b.z, b.w};
  float m = e[0];
#pragma unroll
  for (int j = 1; j < 8; ++j) m = fmaxf(m, e[j]);
#pragma unroll
  for (int o = 32; o; o >>= 1) m = fmaxf(m, __shfl_xor(m, o));
  if ((t & 63) == 0) red[t >> 6] = m;
  __syncthreads();
  m = fmaxf(fmaxf(red[0], red[1]), fmaxf(red[2], red[3]));
  float s = 0.f;
#pragma unroll
  for (int j = 0; j < 8; ++j) { e[j] = __expf(e[j] - m); s += e[j]; }
#pragma unroll
  for (int o = 32; o; o >>= 1) s += __shfl_xor(s, o);
  if ((t & 63) == 0) red[4 + (t >> 6)] = s;
  __syncthreads();
  s = red[4] + red[5] + red[6] + red[7];
  const float inv = 1.0f / s;
  bf16x8 o8;
#pragma unroll
  for (int j = 0; j < 8; ++j) o8[j] = (bf16)(e[j] * inv);
  *(bf16x8*)(pr + t * 8) = o8;
}

extern "C" void kernel_launch(void* const* d_in, const int* in_sizes, int n_in,
                              void* d_out, int out_size, void* d_ws, size_t ws_size,
                              hipStream_t stream) {
  const float* x  = (const float*)d_in[0];
  const float* Wq = (const float*)d_in[1];
  const float* Wk = (const float*)d_in[2];
  const float* Wv = (const float*)d_in[3];
  float* out = (float*)d_out;

  const int D = 1024;

  // workspace (117.44 MB):
  //  [0, 33.55M)        QKbuf bf16 [8192][2048]  -> later P (softmax out)
  //  [33.55M, 50.33M)   Vt bf16 [4][1024][2048]  (written by proj epilogue)
  //  [50.33M, 117.44M)  scores fp32 [4][2048][2048]
  //     (pre-QK this region holds xb @50.33M (16.78M), Wb @67.11M (6.29M))
  char* ws = (char*)d_ws;
  bf16* QKbuf = (bf16*)(ws);
  bf16* P     = (bf16*)(ws);
  bf16* Vt    = (bf16*)(ws + 33554432);
  float* sc   = (float*)(ws + 50331648);
  bf16* xb    = (bf16*)(ws + 50331648);
  bf16* Wb    = (bf16*)(ws + 67108864);

  dim3 b256(256, 1, 1), b512(512, 1, 1);

  // 1) convert inputs to bf16 (weights packed [3][1024][1024])
  cvt_f32_bf16<<<2048, b256, 0, stream>>>(x, xb, 8192 * 1024 / 4);
  cvt_f32_bf16<<<512, b256, 0, stream>>>(Wq, Wb,             D * D / 4);
  cvt_f32_bf16<<<512, b256, 0, stream>>>(Wk, Wb + 1048576,   D * D / 4);
  cvt_f32_bf16<<<512, b256, 0, stream>>>(Wv, Wb + 2097152,   D * D / 4);

  // 2) fused QKV proj: [8192,3072] = xb @ Wb^T; Q/K packed -> QKbuf, V^T -> Vt
  //    768 blocks = 3 exact occupancy rounds
  gemm8<0, 128><<<dim3(24, 32, 1), b512, 0, stream>>>(
      xb, Wb, QKbuf, Vt, 1024, 1024, 2048, 0, 0, 0, 1024, 1.f);

  // 3) scores = Q @ K^T / 32 (batched; 256 blocks = 1 round)
  gemm8<1, 256><<<dim3(8, 8, 4), b512, 0, stream>>>(
      QKbuf, QKbuf + 1024, sc, nullptr, 2048, 2048, 2048,
      4194304, 4194304, 4194304, 1024, 0.03125f);

  // 4) softmax rows -> bf16 P (overwrites dead QKbuf)
  softmax_k<<<8192, b256, 0, stream>>>(sc, P, 2048);

  // 5) out = P @ Vt^T (batched; 256 blocks = 1 round)
  gemm8<1, 128><<<dim3(8, 8, 4), b512, 0, stream>>>(
      P, Vt, out, nullptr, 2048, 2048, 1024,
      4194304, 2097152, 2097152, 2048, 1.f);
}

// Round 4
// 184.923 us; speedup vs baseline: 1.4079x; 1.0266x over previous
//
#include <hip/hip_runtime.h>
#include <stdint.h>

typedef __bf16 bf16;
typedef __bf16 bf16x8 __attribute__((ext_vector_type(8)));
typedef __bf16 bf16x4 __attribute__((ext_vector_type(4)));
typedef float f32x4 __attribute__((ext_vector_type(4)));

__device__ inline void gload_lds16(const void* g, void* l) {
  __builtin_amdgcn_global_load_lds(
      (__attribute__((address_space(1))) void*)g,
      (__attribute__((address_space(3))) void*)l, 16, 0, 0);
}

// ---------------- fp32 -> bf16 conversion (vectorized) ----------------
__global__ __launch_bounds__(256) void cvt_f32_bf16(const float* __restrict__ in,
                                                    bf16* __restrict__ out, int n4) {
  int i = blockIdx.x * blockDim.x + threadIdx.x;
  int stride = gridDim.x * blockDim.x;
  for (; i < n4; i += stride) {
    float4 v = ((const float4*)in)[i];
    bf16x4 o;
    o[0] = (bf16)v.x; o[1] = (bf16)v.y; o[2] = (bf16)v.z; o[3] = (bf16)v.w;
    ((bf16x4*)out)[i] = o;
  }
}

// =====================================================================
// 8-phase GEMM, BM=256, BK=64, 512 threads.  C[M,N] = A[M,K]*B[N,K]^T.
// BN=256: waves 2Mx4N (wave tile 128x64), LDS 128K, B-frags cached across
//         MH phases (24 ds_read_b128/wave/K-tile instead of 32).
// BN=128: waves 4Mx2N (wave tile 64x64), LDS 96K, 2 phases per K-tile.
// Swizzled conflict-free LDS regions (verified 0 bank conflicts r2/r3).
// MODE 0: proj epilogue (col<2048 -> bf16 C ld 2048; col>=2048 -> V^T
//         into C2g as [4][1024][2048])
// MODE 1: fp32 out with scale.   MODE 2: bf16 out with scale.
// =====================================================================
template <int MODE, int BN>
__global__ __launch_bounds__(512, 2) void gemm8(
    const bf16* __restrict__ Ag, const bf16* __restrict__ Bg,
    void* __restrict__ Cg, void* __restrict__ C2g,
    long lda, long ldb, long ldc,
    long sA, long sB, long sC, int K, float scale)
{
  constexpr int BUFSZ = 32768 + BN * 128;
  constexpr int MACC = (BN == 256) ? 8 : 4;
  __shared__ alignas(16) char lds[2 * BUFSZ];
  const int tid = threadIdx.x;
  const int l = tid & 63;
  const int wv = tid >> 6;
  const int fr = l & 15;
  const int kch = l >> 4;
  const int m0 = blockIdx.y * 256;
  const int n0 = blockIdx.x * BN;
  const bf16* Ab = Ag + (long)blockIdx.z * sA;
  const bf16* Bb = Bg + (long)blockIdx.z * sB;

  const int wm = (BN == 256) ? (wv >> 2) : (wv >> 1);
  const int wn = (BN == 256) ? (wv & 3) : (wv & 1);

  // fragment-read byte offsets
  int a_rd, b_rd;
  if constexpr (BN == 256) {
    a_rd = fr * 128 + (((wm * 4 + kch) ^ (fr & 7)) << 4);
    b_rd = (wn & 1) * 8192 + fr * 128 + ((((wn >> 1) * 4 + kch) ^ (fr & 7)) << 4);
  } else {
    a_rd = (wm & 1) * 8192 + fr * 128 + ((((wm >> 1) * 4 + kch) ^ (fr & 7)) << 4);
    b_rd = fr * 128 + (((wn * 4 + kch) ^ (fr & 7)) << 4);
  }

  // staging (inverse swizzle), linear LDS dest
  const int se = (tid & 7) ^ ((tid >> 3) & 7);
  const int s_rowA = (se >> 2) * 128 + (tid >> 3);
  const int s_rowB = (BN == 256) ? s_rowA : ((se >> 2) * 64 + (tid >> 3));
  const int s_k = (se & 3) * 8;
  const int wb16 = (tid & 448) * 16;

  const int NT = K >> 6;
  f32x4 acc[MACC][4] = {};

  auto stageA = [&](int tile, int kh, int buf) {
#pragma unroll
    for (int rd = 0; rd < 2; ++rd)
      gload_lds16(Ab + (long)(m0 + s_rowA + rd * 64) * lda + tile * 64 + kh * 32 + s_k,
                  lds + buf * BUFSZ + kh * 16384 + rd * 8192 + wb16);
  };
  auto stageB = [&](int tile, int kh, int buf) {
    if constexpr (BN == 256) {
#pragma unroll
      for (int rd = 0; rd < 2; ++rd)
        gload_lds16(Bb + (long)(n0 + s_rowB + rd * 64) * ldb + tile * 64 + kh * 32 + s_k,
                    lds + buf * BUFSZ + 32768 + kh * 16384 + rd * 8192 + wb16);
    } else {
      gload_lds16(Bb + (long)(n0 + s_rowB) * ldb + tile * 64 + kh * 32 + s_k,
                  lds + buf * BUFSZ + 32768 + kh * 8192 + wb16);
    }
  };

  // prologue: tile0 fully -> buf0, tile1 k0 -> buf1
  stageA(0, 0, 0); stageB(0, 0, 0); stageA(0, 1, 0); stageB(0, 1, 0);
  stageA(min(1, NT - 1), 0, 1); stageB(min(1, NT - 1), 0, 1);
  if constexpr (BN == 256) asm volatile("s_waitcnt vmcnt(4)" ::: "memory");
  else                     asm volatile("s_waitcnt vmcnt(3)" ::: "memory");
  __builtin_amdgcn_sched_barrier(0);
  __builtin_amdgcn_s_barrier();

  for (int t = 0; t < NT; ++t) {
    const char* bufA = lds + (t & 1) * BUFSZ;
    const char* bufB = bufA + 32768;
    const int t1 = min(t + 1, NT - 1);
    const int t2 = min(t + 2, NT - 1);
    const int nb = (t & 1) ^ 1;
    const int cur = t & 1;

    if constexpr (BN == 256) {
      bf16x8 bfg[4], af[4];
      // P1: B(KH0) + A(KH0,MH0)
#pragma unroll
      for (int n = 0; n < 4; ++n) bfg[n] = *(const bf16x8*)(bufB + n * 2048 + b_rd);
#pragma unroll
      for (int m = 0; m < 4; ++m) af[m] = *(const bf16x8*)(bufA + m * 2048 + a_rd);
      stageA(t1, 1, nb);
      __builtin_amdgcn_s_barrier();
      __builtin_amdgcn_s_setprio(1);
#pragma unroll
      for (int m = 0; m < 4; ++m)
#pragma unroll
        for (int n = 0; n < 4; ++n)
          acc[m][n] = __builtin_amdgcn_mfma_f32_16x16x32_bf16(af[m], bfg[n], acc[m][n], 0, 0, 0);
      __builtin_amdgcn_s_setprio(0);
      __builtin_amdgcn_s_barrier();
      // P2: A(KH0,MH1), B cached
#pragma unroll
      for (int m = 0; m < 4; ++m) af[m] = *(const bf16x8*)(bufA + 8192 + m * 2048 + a_rd);
      stageB(t1, 1, nb);
      __builtin_amdgcn_s_barrier();
      __builtin_amdgcn_s_setprio(1);
#pragma unroll
      for (int m = 0; m < 4; ++m)
#pragma unroll
        for (int n = 0; n < 4; ++n)
          acc[4 + m][n] = __builtin_amdgcn_mfma_f32_16x16x32_bf16(af[m], bfg[n], acc[4 + m][n], 0, 0, 0);
      __builtin_amdgcn_s_setprio(0);
      __builtin_amdgcn_s_barrier();
      // P3: B(KH1) + A(KH1,MH0)
#pragma unroll
      for (int n = 0; n < 4; ++n) bfg[n] = *(const bf16x8*)(bufB + 16384 + n * 2048 + b_rd);
#pragma unroll
      for (int m = 0; m < 4; ++m) af[m] = *(const bf16x8*)(bufA + 16384 + m * 2048 + a_rd);
      stageA(t2, 0, cur);
      __builtin_amdgcn_s_barrier();
      __builtin_amdgcn_s_setprio(1);
#pragma unroll
      for (int m = 0; m < 4; ++m)
#pragma unroll
        for (int n = 0; n < 4; ++n)
          acc[m][n] = __builtin_amdgcn_mfma_f32_16x16x32_bf16(af[m], bfg[n], acc[m][n], 0, 0, 0);
      __builtin_amdgcn_s_setprio(0);
      __builtin_amdgcn_s_barrier();
      // P4: A(KH1,MH1), B cached
#pragma unroll
      for (int m = 0; m < 4; ++m) af[m] = *(const bf16x8*)(bufA + 16384 + 8192 + m * 2048 + a_rd);
      stageB(t2, 0, cur);
      __builtin_amdgcn_s_barrier();
      __builtin_amdgcn_s_setprio(1);
#pragma unroll
      for (int m = 0; m < 4; ++m)
#pragma unroll
        for (int n = 0; n < 4; ++n)
          acc[4 + m][n] = __builtin_amdgcn_mfma_f32_16x16x32_bf16(af[m], bfg[n], acc[4 + m][n], 0, 0, 0);
      __builtin_amdgcn_s_setprio(0);
      asm volatile("s_waitcnt vmcnt(4)" ::: "memory");
      __builtin_amdgcn_sched_barrier(0);
      __builtin_amdgcn_s_barrier();
    } else {
      bf16x8 bfg[4], af[4];
      // P1: KH0
#pragma unroll
      for (int n = 0; n < 4; ++n) bfg[n] = *(const bf16x8*)(bufB + n * 2048 + b_rd);
#pragma unroll
      for (int m = 0; m < 4; ++m) af[m] = *(const bf16x8*)(bufA + m * 2048 + a_rd);
      stageA(t1, 1, nb); stageB(t1, 1, nb);
      __builtin_amdgcn_s_barrier();
      __builtin_amdgcn_s_setprio(1);
#pragma unroll
      for (int m = 0; m < 4; ++m)
#pragma unroll
        for (int n = 0; n < 4; ++n)
          acc[m][n] = __builtin_amdgcn_mfma_f32_16x16x32_bf16(af[m], bfg[n], acc[m][n], 0, 0, 0);
      __builtin_amdgcn_s_setprio(0);
      __builtin_amdgcn_s_barrier();
      // P2: KH1
#pragma unroll
      for (int n = 0; n < 4; ++n) bfg[n] = *(const bf16x8*)(bufB + 8192 + n * 2048 + b_rd);
#pragma unroll
      for (int m = 0; m < 4; ++m) af[m] = *(const bf16x8*)(bufA + 16384 + m * 2048 + a_rd);
      stageA(t2, 0, cur); stageB(t2, 0, cur);
      __builtin_amdgcn_s_barrier();
      __builtin_amdgcn_s_setprio(1);
#pragma unroll
      for (int m = 0; m < 4; ++m)
#pragma unroll
        for (int n = 0; n < 4; ++n)
          acc[m][n] = __builtin_amdgcn_mfma_f32_16x16x32_bf16(af[m], bfg[n], acc[m][n], 0, 0, 0);
      __builtin_amdgcn_s_setprio(0);
      asm volatile("s_waitcnt vmcnt(3)" ::: "memory");
      __builtin_amdgcn_sched_barrier(0);
      __builtin_amdgcn_s_barrier();
    }
  }
  asm volatile("s_waitcnt vmcnt(0)" ::: "memory");

  // epilogue: C/D layout col=lane&15, row=(lane>>4)*4+reg
#pragma unroll
  for (int mf = 0; mf < MACC; ++mf) {
    int row;
    if constexpr (BN == 256)
      row = m0 + wm * 128 + (mf >> 2) * 64 + (mf & 3) * 16 + (l >> 4) * 4;
    else
      row = m0 + wm * 64 + mf * 16 + (l >> 4) * 4;
#pragma unroll
    for (int n = 0; n < 4; ++n) {
      const int col = n0 + wn * 64 + n * 16 + fr;
      if constexpr (MODE == 0) {
        if (col < 2048) {
          bf16* C = (bf16*)Cg;
#pragma unroll
          for (int r = 0; r < 4; ++r)
            C[(long)(row + r) * 2048 + col] = (bf16)acc[mf][n][r];
        } else {
          bf16* Vt = (bf16*)C2g;
          const int d = col - 2048;
          const int b = row >> 11;
          const int s = row & 2047;
          bf16x4 pk;
#pragma unroll
          for (int r = 0; r < 4; ++r) pk[r] = (bf16)acc[mf][n][r];
          *(bf16x4*)(Vt + (long)b * 2097152 + (long)d * 2048 + s) = pk;
        }
      } else if constexpr (MODE == 1) {
        float* C = (float*)Cg + (long)blockIdx.z * sC;
#pragma unroll
        for (int r = 0; r < 4; ++r)
          C[(long)(row + r) * ldc + col] = acc[mf][n][r] * scale;
      } else {
        bf16* C = (bf16*)Cg + (long)blockIdx.z * sC;
#pragma unroll
        for (int r = 0; r < 4; ++r)
          C[(long)(row + r) * ldc + col] = (bf16)(acc[mf][n][r] * scale);
      }
    }
  }
}

// ---------------- row softmax: bf16 scores -> bf16 P ----------------
__global__ __launch_bounds__(256) void softmax_k(const bf16* __restrict__ Sm,
                                                 bf16* __restrict__ P, int cols) {
  __shared__ float red[8];
  const long row = blockIdx.x;
  const bf16* sr = Sm + row * (long)cols;
  bf16* pr = P + row * (long)cols;
  const int t = threadIdx.x;
  bf16x8 v = *(const bf16x8*)(sr + t * 8);
  float e[8];
#pragma unroll
  for (int j = 0; j < 8; ++j) e[j] = (float)v[j];
  float m = e[0];
#pragma unroll
  for (int j = 1; j < 8; ++j) m = fmaxf(m, e[j]);
#pragma unroll
  for (int o = 32; o; o >>= 1) m = fmaxf(m, __shfl_xor(m, o));
  if ((t & 63) == 0) red[t >> 6] = m;
  __syncthreads();
  m = fmaxf(fmaxf(red[0], red[1]), fmaxf(red[2], red[3]));
  float s = 0.f;
#pragma unroll
  for (int j = 0; j < 8; ++j) { e[j] = __expf(e[j] - m); s += e[j]; }
#pragma unroll
  for (int o = 32; o; o >>= 1) s += __shfl_xor(s, o);
  if ((t & 63) == 0) red[4 + (t >> 6)] = s;
  __syncthreads();
  s = red[4] + red[5] + red[6] + red[7];
  const float inv = 1.0f / s;
  bf16x8 o8;
#pragma unroll
  for (int j = 0; j < 8; ++j) o8[j] = (bf16)(e[j] * inv);
  *(bf16x8*)(pr + t * 8) = o8;
}

extern "C" void kernel_launch(void* const* d_in, const int* in_sizes, int n_in,
                              void* d_out, int out_size, void* d_ws, size_t ws_size,
                              hipStream_t stream) {
  const float* x  = (const float*)d_in[0];
  const float* Wq = (const float*)d_in[1];
  const float* Wk = (const float*)d_in[2];
  const float* Wv = (const float*)d_in[3];
  float* out = (float*)d_out;

  const int D = 1024;

  // workspace (117.44 MB):
  //  [0, 33.55M)        QKbuf bf16 [8192][2048]  -> later P (softmax out)
  //  [33.55M, 50.33M)   Vt bf16 [4][1024][2048]  (written by proj epilogue)
  //  [50.33M, 83.89M)   scores bf16 [4][2048][2048]
  //     (pre-QK this region holds xb @50.33M (16.78M), Wb @67.11M (6.29M))
  char* ws = (char*)d_ws;
  bf16* QKbuf = (bf16*)(ws);
  bf16* P     = (bf16*)(ws);
  bf16* Vt    = (bf16*)(ws + 33554432);
  bf16* scb   = (bf16*)(ws + 50331648);
  bf16* xb    = (bf16*)(ws + 50331648);
  bf16* Wb    = (bf16*)(ws + 67108864);

  dim3 b256(256, 1, 1), b512(512, 1, 1);

  // 1) convert inputs to bf16 (weights packed [3][1024][1024])
  cvt_f32_bf16<<<2048, b256, 0, stream>>>(x, xb, 8192 * 1024 / 4);
  cvt_f32_bf16<<<512, b256, 0, stream>>>(Wq, Wb,             D * D / 4);
  cvt_f32_bf16<<<512, b256, 0, stream>>>(Wk, Wb + 1048576,   D * D / 4);
  cvt_f32_bf16<<<512, b256, 0, stream>>>(Wv, Wb + 2097152,   D * D / 4);

  // 2) fused QKV proj (BN=256, B-cached): [8192,3072] = xb @ Wb^T
  //    Q/K packed -> QKbuf, V^T -> Vt
  gemm8<0, 256><<<dim3(12, 32, 1), b512, 0, stream>>>(
      xb, Wb, QKbuf, Vt, 1024, 1024, 2048, 0, 0, 0, 1024, 1.f);

  // 3) scores = Q @ K^T / 32 -> bf16 (batched; 256 blocks = 1 round)
  gemm8<2, 256><<<dim3(8, 8, 4), b512, 0, stream>>>(
      QKbuf, QKbuf + 1024, scb, nullptr, 2048, 2048, 2048,
      4194304, 4194304, 4194304, 1024, 0.03125f);

  // 4) softmax rows (bf16 in) -> bf16 P (overwrites dead QKbuf)
  softmax_k<<<8192, b256, 0, stream>>>(scb, P, 2048);

  // 5) out = P @ Vt^T (batched; 256 blocks = 1 round)
  gemm8<1, 128><<<dim3(8, 8, 4), b512, 0, stream>>>(
      P, Vt, out, nullptr, 2048, 2048, 1024,
      4194304, 2097152, 2097152, 2048, 1.f);
}

// Round 5
// 183.674 us; speedup vs baseline: 1.4174x; 1.0068x over previous
//
#include <hip/hip_runtime.h>
#include <stdint.h>

typedef __bf16 bf16;
typedef __bf16 bf16x8 __attribute__((ext_vector_type(8)));
typedef __bf16 bf16x4 __attribute__((ext_vector_type(4)));
typedef float f32x4 __attribute__((ext_vector_type(4)));

__device__ inline void gload_lds16(const void* g, void* l) {
  __builtin_amdgcn_global_load_lds(
      (__attribute__((address_space(1))) void*)g,
      (__attribute__((address_space(3))) void*)l, 16, 0, 0);
}

// ---------------- fp32 -> bf16 conversion (vectorized) ----------------
__global__ __launch_bounds__(256) void cvt_f32_bf16(const float* __restrict__ in,
                                                    bf16* __restrict__ out, int n4) {
  int i = blockIdx.x * blockDim.x + threadIdx.x;
  int stride = gridDim.x * blockDim.x;
  for (; i < n4; i += stride) {
    float4 v = ((const float4*)in)[i];
    bf16x4 o;
    o[0] = (bf16)v.x; o[1] = (bf16)v.y; o[2] = (bf16)v.z; o[3] = (bf16)v.w;
    ((bf16x4*)out)[i] = o;
  }
}

// =====================================================================
// 8-phase GEMM, BM=256, BK=64, 512 threads.  C[M,N] = A[M,K]*B[N,K]^T.
// BN=256: waves 2Mx4N (wave tile 128x64), LDS 128K, B-frags cached across
//         MH phases.  Use ONLY at exact-round grids (256 blocks).
// BN=128: waves 4Mx2N (wave tile 64x64), LDS 96K, 2 phases per K-tile.
// Stage-first phases (T3): global_load_lds issued at phase top, covered
// by the phase's ds_read + barrier + MFMA before tile-end vmcnt.
// Swizzled conflict-free LDS regions (verified 0 bank conflicts r2-r4).
// MODE 0: proj epilogue (col<2048 -> bf16 C ld 2048; col>=2048 -> V^T
//         into C2g as [4][1024][2048])
// MODE 1: fp32 out with scale.   MODE 2: bf16 out with scale.
// =====================================================================
template <int MODE, int BN>
__global__ __launch_bounds__(512, 2) void gemm8(
    const bf16* __restrict__ Ag, const bf16* __restrict__ Bg,
    void* __restrict__ Cg, void* __restrict__ C2g,
    long lda, long ldb, long ldc,
    long sA, long sB, long sC, int K, float scale)
{
  constexpr int BUFSZ = 32768 + BN * 128;
  constexpr int MACC = (BN == 256) ? 8 : 4;
  __shared__ alignas(16) char lds[2 * BUFSZ];
  const int tid = threadIdx.x;
  const int l = tid & 63;
  const int wv = tid >> 6;
  const int fr = l & 15;
  const int kch = l >> 4;
  const int m0 = blockIdx.y * 256;
  const int n0 = blockIdx.x * BN;
  const bf16* Ab = Ag + (long)blockIdx.z * sA;
  const bf16* Bb = Bg + (long)blockIdx.z * sB;

  const int wm = (BN == 256) ? (wv >> 2) : (wv >> 1);
  const int wn = (BN == 256) ? (wv & 3) : (wv & 1);

  // fragment-read byte offsets
  int a_rd, b_rd;
  if constexpr (BN == 256) {
    a_rd = fr * 128 + (((wm * 4 + kch) ^ (fr & 7)) << 4);
    b_rd = (wn & 1) * 8192 + fr * 128 + ((((wn >> 1) * 4 + kch) ^ (fr & 7)) << 4);
  } else {
    a_rd = (wm & 1) * 8192 + fr * 128 + ((((wm >> 1) * 4 + kch) ^ (fr & 7)) << 4);
    b_rd = fr * 128 + (((wn * 4 + kch) ^ (fr & 7)) << 4);
  }

  // staging (inverse swizzle), linear LDS dest
  const int se = (tid & 7) ^ ((tid >> 3) & 7);
  const int s_rowA = (se >> 2) * 128 + (tid >> 3);
  const int s_rowB = (BN == 256) ? s_rowA : ((se >> 2) * 64 + (tid >> 3));
  const int s_k = (se & 3) * 8;
  const int wb16 = (tid & 448) * 16;

  const int NT = K >> 6;
  f32x4 acc[MACC][4] = {};

  auto stageA = [&](int tile, int kh, int buf) {
#pragma unroll
    for (int rd = 0; rd < 2; ++rd)
      gload_lds16(Ab + (long)(m0 + s_rowA + rd * 64) * lda + tile * 64 + kh * 32 + s_k,
                  lds + buf * BUFSZ + kh * 16384 + rd * 8192 + wb16);
  };
  auto stageB = [&](int tile, int kh, int buf) {
    if constexpr (BN == 256) {
#pragma unroll
      for (int rd = 0; rd < 2; ++rd)
        gload_lds16(Bb + (long)(n0 + s_rowB + rd * 64) * ldb + tile * 64 + kh * 32 + s_k,
                    lds + buf * BUFSZ + 32768 + kh * 16384 + rd * 8192 + wb16);
    } else {
      gload_lds16(Bb + (long)(n0 + s_rowB) * ldb + tile * 64 + kh * 32 + s_k,
                  lds + buf * BUFSZ + 32768 + kh * 8192 + wb16);
    }
  };

  // prologue: tile0 fully -> buf0, tile1 k0 -> buf1
  stageA(0, 0, 0); stageB(0, 0, 0); stageA(0, 1, 0); stageB(0, 1, 0);
  stageA(min(1, NT - 1), 0, 1); stageB(min(1, NT - 1), 0, 1);
  if constexpr (BN == 256) asm volatile("s_waitcnt vmcnt(4)" ::: "memory");
  else                     asm volatile("s_waitcnt vmcnt(3)" ::: "memory");
  __builtin_amdgcn_sched_barrier(0);
  __builtin_amdgcn_s_barrier();

  for (int t = 0; t < NT; ++t) {
    const char* bufA = lds + (t & 1) * BUFSZ;
    const char* bufB = bufA + 32768;
    const int t1 = min(t + 1, NT - 1);
    const int t2 = min(t + 2, NT - 1);
    const int nb = (t & 1) ^ 1;
    const int cur = t & 1;

    if constexpr (BN == 256) {
      bf16x8 bfg[4], af[4];
      // P1: stage A(t+1,k1) first; read B(KH0) + A(KH0,MH0)
      stageA(t1, 1, nb);
#pragma unroll
      for (int n = 0; n < 4; ++n) bfg[n] = *(const bf16x8*)(bufB + n * 2048 + b_rd);
#pragma unroll
      for (int m = 0; m < 4; ++m) af[m] = *(const bf16x8*)(bufA + m * 2048 + a_rd);
      __builtin_amdgcn_s_barrier();
      __builtin_amdgcn_s_setprio(1);
#pragma unroll
      for (int m = 0; m < 4; ++m)
#pragma unroll
        for (int n = 0; n < 4; ++n)
          acc[m][n] = __builtin_amdgcn_mfma_f32_16x16x32_bf16(af[m], bfg[n], acc[m][n], 0, 0, 0);
      __builtin_amdgcn_s_setprio(0);
      __builtin_amdgcn_s_barrier();
      // P2: stage B(t+1,k1); read A(KH0,MH1); B cached
      stageB(t1, 1, nb);
#pragma unroll
      for (int m = 0; m < 4; ++m) af[m] = *(const bf16x8*)(bufA + 8192 + m * 2048 + a_rd);
      __builtin_amdgcn_s_barrier();
      __builtin_amdgcn_s_setprio(1);
#pragma unroll
      for (int m = 0; m < 4; ++m)
#pragma unroll
        for (int n = 0; n < 4; ++n)
          acc[4 + m][n] = __builtin_amdgcn_mfma_f32_16x16x32_bf16(af[m], bfg[n], acc[4 + m][n], 0, 0, 0);
      __builtin_amdgcn_s_setprio(0);
      __builtin_amdgcn_s_barrier();
      // P3: stage A(t+2,k0); read B(KH1) + A(KH1,MH0)
      stageA(t2, 0, cur);
#pragma unroll
      for (int n = 0; n < 4; ++n) bfg[n] = *(const bf16x8*)(bufB + 16384 + n * 2048 + b_rd);
#pragma unroll
      for (int m = 0; m < 4; ++m) af[m] = *(const bf16x8*)(bufA + 16384 + m * 2048 + a_rd);
      __builtin_amdgcn_s_barrier();
      __builtin_amdgcn_s_setprio(1);
#pragma unroll
      for (int m = 0; m < 4; ++m)
#pragma unroll
        for (int n = 0; n < 4; ++n)
          acc[m][n] = __builtin_amdgcn_mfma_f32_16x16x32_bf16(af[m], bfg[n], acc[m][n], 0, 0, 0);
      __builtin_amdgcn_s_setprio(0);
      __builtin_amdgcn_s_barrier();
      // P4: stage B(t+2,k0); read A(KH1,MH1); B cached
      stageB(t2, 0, cur);
#pragma unroll
      for (int m = 0; m < 4; ++m) af[m] = *(const bf16x8*)(bufA + 16384 + 8192 + m * 2048 + a_rd);
      __builtin_amdgcn_s_barrier();
      __builtin_amdgcn_s_setprio(1);
#pragma unroll
      for (int m = 0; m < 4; ++m)
#pragma unroll
        for (int n = 0; n < 4; ++n)
          acc[4 + m][n] = __builtin_amdgcn_mfma_f32_16x16x32_bf16(af[m], bfg[n], acc[4 + m][n], 0, 0, 0);
      __builtin_amdgcn_s_setprio(0);
      asm volatile("s_waitcnt vmcnt(4)" ::: "memory");
      __builtin_amdgcn_sched_barrier(0);
      __builtin_amdgcn_s_barrier();
    } else {
      bf16x8 bfg[4], af[4];
      // P1: stage A+B(t+1,k1) first; read KH0
      stageA(t1, 1, nb); stageB(t1, 1, nb);
#pragma unroll
      for (int n = 0; n < 4; ++n) bfg[n] = *(const bf16x8*)(bufB + n * 2048 + b_rd);
#pragma unroll
      for (int m = 0; m < 4; ++m) af[m] = *(const bf16x8*)(bufA + m * 2048 + a_rd);
      __builtin_amdgcn_s_barrier();
      __builtin_amdgcn_s_setprio(1);
#pragma unroll
      for (int m = 0; m < 4; ++m)
#pragma unroll
        for (int n = 0; n < 4; ++n)
          acc[m][n] = __builtin_amdgcn_mfma_f32_16x16x32_bf16(af[m], bfg[n], acc[m][n], 0, 0, 0);
      __builtin_amdgcn_s_setprio(0);
      __builtin_amdgcn_s_barrier();
      // P2: stage A+B(t+2,k0); read KH1
      stageA(t2, 0, cur); stageB(t2, 0, cur);
#pragma unroll
      for (int n = 0; n < 4; ++n) bfg[n] = *(const bf16x8*)(bufB + 8192 + n * 2048 + b_rd);
#pragma unroll
      for (int m = 0; m < 4; ++m) af[m] = *(const bf16x8*)(bufA + 16384 + m * 2048 + a_rd);
      __builtin_amdgcn_s_barrier();
      __builtin_amdgcn_s_setprio(1);
#pragma unroll
      for (int m = 0; m < 4; ++m)
#pragma unroll
        for (int n = 0; n < 4; ++n)
          acc[m][n] = __builtin_amdgcn_mfma_f32_16x16x32_bf16(af[m], bfg[n], acc[m][n], 0, 0, 0);
      __builtin_amdgcn_s_setprio(0);
      asm volatile("s_waitcnt vmcnt(3)" ::: "memory");
      __builtin_amdgcn_sched_barrier(0);
      __builtin_amdgcn_s_barrier();
    }
  }
  asm volatile("s_waitcnt vmcnt(0)" ::: "memory");

  // epilogue: C/D layout col=lane&15, row=(lane>>4)*4+reg
#pragma unroll
  for (int mf = 0; mf < MACC; ++mf) {
    int row;
    if constexpr (BN == 256)
      row = m0 + wm * 128 + (mf >> 2) * 64 + (mf & 3) * 16 + (l >> 4) * 4;
    else
      row = m0 + wm * 64 + mf * 16 + (l >> 4) * 4;
#pragma unroll
    for (int n = 0; n < 4; ++n) {
      const int col = n0 + wn * 64 + n * 16 + fr;
      if constexpr (MODE == 0) {
        if (col < 2048) {
          bf16* C = (bf16*)Cg;
#pragma unroll
          for (int r = 0; r < 4; ++r)
            C[(long)(row + r) * 2048 + col] = (bf16)acc[mf][n][r];
        } else {
          bf16* Vt = (bf16*)C2g;
          const int d = col - 2048;
          const int b = row >> 11;
          const int s = row & 2047;
          bf16x4 pk;
#pragma unroll
          for (int r = 0; r < 4; ++r) pk[r] = (bf16)acc[mf][n][r];
          *(bf16x4*)(Vt + (long)b * 2097152 + (long)d * 2048 + s) = pk;
        }
      } else if constexpr (MODE == 1) {
        float* C = (float*)Cg + (long)blockIdx.z * sC;
#pragma unroll
        for (int r = 0; r < 4; ++r)
          C[(long)(row + r) * ldc + col] = acc[mf][n][r] * scale;
      } else {
        bf16* C = (bf16*)Cg + (long)blockIdx.z * sC;
#pragma unroll
        for (int r = 0; r < 4; ++r)
          C[(long)(row + r) * ldc + col] = (bf16)(acc[mf][n][r] * scale);
      }
    }
  }
}

// ---------------- row softmax: bf16 scores -> bf16 P ----------------
__global__ __launch_bounds__(256) void softmax_k(const bf16* __restrict__ Sm,
                                                 bf16* __restrict__ P, int cols) {
  __shared__ float red[8];
  const long row = blockIdx.x;
  const bf16* sr = Sm + row * (long)cols;
  bf16* pr = P + row * (long)cols;
  const int t = threadIdx.x;
  bf16x8 v = *(const bf16x8*)(sr + t * 8);
  float e[8];
#pragma unroll
  for (int j = 0; j < 8; ++j) e[j] = (float)v[j];
  float m = e[0];
#pragma unroll
  for (int j = 1; j < 8; ++j) m = fmaxf(m, e[j]);
#pragma unroll
  for (int o = 32; o; o >>= 1) m = fmaxf(m, __shfl_xor(m, o));
  if ((t & 63) == 0) red[t >> 6] = m;
  __syncthreads();
  m = fmaxf(fmaxf(red[0], red[1]), fmaxf(red[2], red[3]));
  float s = 0.f;
#pragma unroll
  for (int j = 0; j < 8; ++j) { e[j] = __expf(e[j] - m); s += e[j]; }
#pragma unroll
  for (int o = 32; o; o >>= 1) s += __shfl_xor(s, o);
  if ((t & 63) == 0) red[4 + (t >> 6)] = s;
  __syncthreads();
  s = red[4] + red[5] + red[6] + red[7];
  const float inv = 1.0f / s;
  bf16x8 o8;
#pragma unroll
  for (int j = 0; j < 8; ++j) o8[j] = (bf16)(e[j] * inv);
  *(bf16x8*)(pr + t * 8) = o8;
}

extern "C" void kernel_launch(void* const* d_in, const int* in_sizes, int n_in,
                              void* d_out, int out_size, void* d_ws, size_t ws_size,
                              hipStream_t stream) {
  const float* x  = (const float*)d_in[0];
  const float* Wq = (const float*)d_in[1];
  const float* Wk = (const float*)d_in[2];
  const float* Wv = (const float*)d_in[3];
  float* out = (float*)d_out;

  const int D = 1024;

  // workspace (117.44 MB):
  //  [0, 33.55M)        QKbuf bf16 [8192][2048]  -> later P (softmax out)
  //  [33.55M, 50.33M)   Vt bf16 [4][1024][2048]  (written by proj epilogue)
  //  [50.33M, 83.89M)   scores bf16 [4][2048][2048]
  //     (pre-QK this region holds xb @50.33M (16.78M), Wb @67.11M (6.29M))
  char* ws = (char*)d_ws;
  bf16* QKbuf = (bf16*)(ws);
  bf16* P     = (bf16*)(ws);
  bf16* Vt    = (bf16*)(ws + 33554432);
  bf16* scb   = (bf16*)(ws + 50331648);
  bf16* xb    = (bf16*)(ws + 50331648);
  bf16* Wb    = (bf16*)(ws + 67108864);

  dim3 b256(256, 1, 1), b512(512, 1, 1);

  // 1) convert inputs to bf16 (weights packed [3][1024][1024])
  cvt_f32_bf16<<<2048, b256, 0, stream>>>(x, xb, 8192 * 1024 / 4);
  cvt_f32_bf16<<<512, b256, 0, stream>>>(Wq, Wb,             D * D / 4);
  cvt_f32_bf16<<<512, b256, 0, stream>>>(Wk, Wb + 1048576,   D * D / 4);
  cvt_f32_bf16<<<512, b256, 0, stream>>>(Wv, Wb + 2097152,   D * D / 4);

  // 2) fused QKV proj (BN=128: 768 blocks = 3 exact rounds):
  //    [8192,3072] = xb @ Wb^T; Q/K packed -> QKbuf, V^T -> Vt
  gemm8<0, 128><<<dim3(24, 32, 1), b512, 0, stream>>>(
      xb, Wb, QKbuf, Vt, 1024, 1024, 2048, 0, 0, 0, 1024, 1.f);

  // 3) scores = Q @ K^T / 32 -> bf16 (batched; 256 blocks = 1 round)
  gemm8<2, 256><<<dim3(8, 8, 4), b512, 0, stream>>>(
      QKbuf, QKbuf + 1024, scb, nullptr, 2048, 2048, 2048,
      4194304, 4194304, 4194304, 1024, 0.03125f);

  // 4) softmax rows (bf16 in) -> bf16 P (overwrites dead QKbuf)
  softmax_k<<<8192, b256, 0, stream>>>(scb, P, 2048);

  // 5) out = P @ Vt^T (batched; 256 blocks = 1 round)
  gemm8<1, 128><<<dim3(8, 8, 4), b512, 0, stream>>>(
      P, Vt, out, nullptr, 2048, 2048, 1024,
      4194304, 2097152, 2097152, 2048, 1.f);
}